// Round 17
// baseline (57.052 us; speedup 1.0000x reference)
//
#include <hip/hip_runtime.h>
#include <hip/hip_bf16.h>

#define OUT_N 8192
#define IN_N  8192
#define QROW  (IN_N / 2)     // 4096 int32 per out row (one widened byte each)
#define NCH   8              // k sub-chunks per wave
#define CH32  64             // int32 per row per sub-chunk (per wave)

typedef __attribute__((ext_vector_type(8))) short short8v;  // 8 bf16
typedef __attribute__((ext_vector_type(4))) float f32x4;

__device__ __forceinline__ unsigned int bf16pk(float a, float b) {
    __hip_bfloat162 h = __float22bfloat162_rn(make_float2(a, b));
    unsigned int u;
    __builtin_memcpy(&u, &h, 4);
    return u;
}

#define SCHED0() __builtin_amdgcn_sched_barrier(0)

// Pre-pass: x fp32 -> bf16 PERMUTED to main-kernel consume order (R15):
// uint4 slot [(w*32 + c*4 + s)*64 + l] = bf16x8 of
// x[row=l&15][w*1024 + c*128 + s*32 + (l>>4)*8 ..+8].
__global__ __launch_bounds__(256) void xconv_kernel(
    const float* __restrict__ x, uint4* __restrict__ xb2)
{
    const int tid = blockIdx.x * 256 + threadIdx.x;   // 16384 uint4 outputs
    const int l   = tid & 63;
    const int scs = tid >> 6;
    const int s   = scs & 3;
    const int c   = (scs >> 2) & 7;
    const int w   = scs >> 5;
    const int r   = l & 15;
    const int g   = l >> 4;
    const float* src = x + (size_t)r * IN_N + w * 1024 + c * 128 + s * 32 + g * 8;
    float4 a = *(const float4*)src;
    float4 b = *(const float4*)(src + 4);
    uint4 u = { bf16pk(a.x, a.y), bf16pk(a.z, a.w),
                bf16pk(b.x, b.y), bf16pk(b.z, b.w) };
    xb2[tid] = u;
}

// R15 skeleton (best: 30.8 us) with q transport switched from global_load_lds
// DMA to reg-staging (global_load_dwordx4 -> VGPR -> ds_write_b128). Same
// addresses, same swizzled-linear LDS layout, same wave-private no-barrier
// counted-vmcnt ledger:
//   top: vmcnt(8)+lgkmcnt(0) -> compute(c) -> vmcnt(4) [q(c+1) regs arrived]
//   -> ds_write q(c+1) -> issue q(c+2)+x(c+2). vmcnt(0) only on last chunk.
// Chunk schedule rotated by ph = tile & 7. Isolates the DMA-path-BW question.
__global__ __launch_bounds__(512, 4) void qlin_mfma_kernel(
    const int*   __restrict__ qp,
    const uint4* __restrict__ xb2,
    const float* __restrict__ scale,
    const float* __restrict__ bias,
    float*       __restrict__ out)
{
    __shared__ int   qbuf[8][2][16 * CH32];   // 8 waves x 2 x 4KB = 64 KB
    __shared__ float red[8][16][17];          // 8.7 KB reduction scratch

    const int t = threadIdx.x;
    const int w = t >> 6;            // wave id -> k range [w*1024, +1024) elems
    const int l = t & 63;
    const int g = l >> 4;            // lane group 0..3
    const int r = l & 15;            // A: batch row, B: out row within tile
    const int tile = blockIdx.x;
    const int obase = tile * 16;
    const int ph = tile & 7;         // chunk-phase rotation for this tile

    const int* qwbase = qp + (size_t)obase * QROW + w * (QROW / 8);
    const int drow = l >> 4;                      // row sub-index (+4p)
    const uint4* xwbase = xb2 + (w << 11) + l;    // permuted x: + c*256 + s*64

    f32x4 acc = {0.f, 0.f, 0.f, 0.f};
    int4  qr[2][4];   // q register staging (32 VGPR)
    uint4 xr[2][4];   // x fragments (32 VGPR)

    // load q chunk c_ into qr[b_]: same per-lane addresses as the DMA version
#define QLD(c_, b_) do { _Pragma("unroll")                                    \
    for (int p = 0; p < 4; ++p) {                                             \
        const int row = 4 * p + drow;                                         \
        qr[b_][p] = *(const int4*)(qwbase + (size_t)row * QROW + (c_) * CH32  \
                                   + (((l & 15) ^ (row & 15)) << 2));         \
    } } while (0)
#define XLD(c_, b_) do { _Pragma("unroll")                                    \
    for (int s = 0; s < 4; ++s) xr[b_][s] = xwbase[(c_) * 256 + s * 64];      \
    } while (0)
    // ds_write qr[b_] to linear LDS dest (lane*16B) == DMA layout
#define QST(b_) do { _Pragma("unroll")                                        \
    for (int p = 0; p < 4; ++p)                                               \
        *(int4*)&qbuf[w][b_][p * 256 + l * 4] = qr[b_][p];                    \
    } while (0)

    // ---- prologue
    QLD(ph, 0); XLD(ph, 0);                       // out: 8
    asm volatile("s_waitcnt vmcnt(0)" ::: "memory");
    SCHED0();
    QST(0);                                       // LDS[0] = chunk(ph)
    {
        const int c1 = (1 + ph) & 7;
        QLD(c1, 1); XLD(c1, 1);                   // out: 8
    }

    #pragma unroll   // full unroll: static buffer indices + static vmcnt imms
    for (int c0 = 0; c0 < NCH; ++c0) {
        const int cur = c0 & 1;

        if (c0 < NCH - 1) asm volatile("s_waitcnt vmcnt(8)" ::: "memory");
        else              asm volatile("s_waitcnt vmcnt(0)" ::: "memory");
        asm volatile("s_waitcnt lgkmcnt(0)" ::: "memory");  // QST(c0) done
        SCHED0();                     // rule #18: pin ds_reads below waits

        const char* wb = (const char*)qbuf[w][cur];
        #pragma unroll
        for (int s = 0; s < 4; ++s) {
            // read slot j0 = s*4+g of row r, stored at slot j0^r (2-way = free)
            const int4 q = *(const int4*)(wb + r * 256 + ((((s << 2) + g) ^ r) << 4));
            // nibble e=2m lo / e=2m+1 hi of byte m; signed; exact in bf16
            uint4 ub = {
                bf16pk((float)((q.x << 28) >> 28), (float)((q.x << 24) >> 28)),
                bf16pk((float)((q.y << 28) >> 28), (float)((q.y << 24) >> 28)),
                bf16pk((float)((q.z << 28) >> 28), (float)((q.z << 24) >> 28)),
                bf16pk((float)((q.w << 28) >> 28), (float)((q.w << 24) >> 28))
            };
            short8v bfrag = __builtin_bit_cast(short8v, ub);
            short8v afrag = __builtin_bit_cast(short8v, xr[cur][s]);
            acc = __builtin_amdgcn_mfma_f32_16x16x32_bf16(afrag, bfrag, acc, 0, 0, 0);
        }

        if (c0 + 1 < NCH) {
            SCHED0();
            asm volatile("s_waitcnt vmcnt(4)" ::: "memory");  // q(c0+1) arrived
            SCHED0();
            QST(cur ^ 1);                         // LDS[cur^1] = chunk(c0+1)
            if (c0 + 2 < NCH) {
                const int cc2 = (c0 + 2 + ph) & 7;
                QLD(cc2, cur); XLD(cc2, cur);     // out: x(c0+1)(<=4) + 8
            }
        }
    }
#undef QLD
#undef XLD
#undef QST

    // ---- cross-wave K reduction; D map: col=lane&15 (out), row=(lane>>4)*4+j
    red[w][g * 4 + 0][r] = acc[0];
    red[w][g * 4 + 1][r] = acc[1];
    red[w][g * 4 + 2][r] = acc[2];
    red[w][g * 4 + 3][r] = acc[3];
    __syncthreads();

    if (t < 256) {
        const int b = t >> 4;            // batch
        const int o = t & 15;            // out within tile
        const int oc = obase + o;
        float v = 0.f;
        #pragma unroll
        for (int i = 0; i < 8; ++i) v += red[i][b][o];
        out[b * OUT_N + oc] = v * scale[oc >> 7] + bias[oc];
    }
}

extern "C" void kernel_launch(void* const* d_in, const int* in_sizes, int n_in,
                              void* d_out, int out_size, void* d_ws, size_t ws_size,
                              hipStream_t stream) {
    (void)in_sizes; (void)n_in; (void)ws_size; (void)out_size;
    const float* x     = (const float*)d_in[0];
    const int*   qp    = (const int*)d_in[1];
    const float* scale = (const float*)d_in[2];
    const float* bias  = (const float*)d_in[3];
    float*       out   = (float*)d_out;
    uint4*       xb2   = (uint4*)d_ws;     // 256 KB permuted bf16 x

    xconv_kernel<<<dim3(64), dim3(256), 0, stream>>>(x, xb2);
    qlin_mfma_kernel<<<dim3(OUT_N / 16), dim3(512), 0, stream>>>(qp, xb2, scale, bias, out);
}

// Round 18
// 30.283 us; speedup vs baseline: 1.8839x; 1.8839x over previous
//
#include <hip/hip_runtime.h>
#include <hip/hip_bf16.h>

#define OUT_N 8192
#define IN_N  8192
#define QROW  (IN_N / 2)     // 4096 int32 per out row (one widened byte each)
#define NCH   8
#define CH32  64             // int32 per row per sub-chunk (256-B granule)

typedef __attribute__((ext_vector_type(8))) short short8v;  // 8 bf16
typedef __attribute__((ext_vector_type(4))) float f32x4;

__device__ __forceinline__ unsigned int bf16pk(float a, float b) {
    __hip_bfloat162 h = __float22bfloat162_rn(make_float2(a, b));
    unsigned int u;
    __builtin_memcpy(&u, &h, 4);
    return u;
}

#define SCHED0() __builtin_amdgcn_sched_barrier(0)
#define WAITV(n) asm volatile("s_waitcnt vmcnt(" #n ")" ::: "memory")
#define WAITL()  asm volatile("s_waitcnt lgkmcnt(0)" ::: "memory")

// Pre-pass: x fp32 -> bf16 PERMUTED to main-kernel consume order (R15):
// uint4 slot [(w*32 + c*4 + s)*64 + l] = bf16x8 of
// x[row=l&15][w*1024 + c*128 + s*32 + (l>>4)*8 ..+8].
__global__ __launch_bounds__(256) void xconv_kernel(
    const float* __restrict__ x, uint4* __restrict__ xb2)
{
    const int tid = blockIdx.x * 256 + threadIdx.x;
    const int l   = tid & 63;
    const int scs = tid >> 6;
    const int s   = scs & 3;
    const int c   = (scs >> 2) & 7;
    const int w   = scs >> 5;
    const int r   = l & 15;
    const int g   = l >> 4;
    const float* src = x + (size_t)r * IN_N + w * 1024 + c * 128 + s * 32 + g * 8;
    float4 a = *(const float4*)src;
    float4 b = *(const float4*)(src + 4);
    uint4 u = { bf16pk(a.x, a.y), bf16pk(a.z, a.w),
                bf16pk(b.x, b.y), bf16pk(b.z, b.w) };
    xb2[tid] = u;
}

// R15 skeleton; q transport = reg-staging (global_load_dwordx4 -> ds_write),
// HAND-UNROLLED with literal buffer tokens everywhere (no runtime-indexed
// arrays -> no scratch; rule #20). Wave-private, no block barrier, counted
// vmcnt ledger (literal immediates). Chunk addresses rotated by ph = tile&7.
__global__ __launch_bounds__(512, 4) void qlin_mfma_kernel(
    const int*   __restrict__ qp,
    const uint4* __restrict__ xb2,
    const float* __restrict__ scale,
    const float* __restrict__ bias,
    float*       __restrict__ out)
{
    __shared__ int   qbuf[8][2][16 * CH32];   // 8 waves x 2 x 4KB = 64 KB
    __shared__ float red[8][16][17];          // 8.7 KB reduction scratch

    const int t = threadIdx.x;
    const int w = t >> 6;
    const int l = t & 63;
    const int g = l >> 4;
    const int r = l & 15;
    const int tile = blockIdx.x;
    const int obase = tile * 16;
    const int ph = tile & 7;

    const int* qwbase = qp + (size_t)obase * QROW + w * (QROW / 8);
    const int drow = l >> 4;
    const uint4* xwbase = xb2 + (w << 11) + l;    // + c*256 + s*64

    f32x4 acc = {0.f, 0.f, 0.f, 0.f};
    int4  qr0, qr1, qr2, qr3;        // single q staging set (16 VGPR)
    uint4 xa0, xa1, xa2, xa3;        // x buffer A (16 VGPR)
    uint4 xb0, xb1, xb2r, xb3;       // x buffer B (16 VGPR)

    // q loads: identical per-lane addresses as the R15 DMA source
#define QLD(c_) do {                                                          \
    const int cc = ((c_) + ph) & 7;                                           \
    const int r0 = 0 + drow, r1 = 4 + drow, r2 = 8 + drow, r3 = 12 + drow;    \
    qr0 = *(const int4*)(qwbase + (size_t)r0 * QROW + cc * CH32 + (((l & 15) ^ r0) << 2)); \
    qr1 = *(const int4*)(qwbase + (size_t)r1 * QROW + cc * CH32 + (((l & 15) ^ r1) << 2)); \
    qr2 = *(const int4*)(qwbase + (size_t)r2 * QROW + cc * CH32 + (((l & 15) ^ r2) << 2)); \
    qr3 = *(const int4*)(qwbase + (size_t)r3 * QROW + cc * CH32 + (((l & 15) ^ r3) << 2)); \
    } while (0)

#define XLD(c_, B0, B1, B2, B3) do {                                          \
    const int cc = ((c_) + ph) & 7;                                           \
    B0 = xwbase[cc * 256 +   0]; B1 = xwbase[cc * 256 +  64];                 \
    B2 = xwbase[cc * 256 + 128]; B3 = xwbase[cc * 256 + 192];                 \
    } while (0)

    // ds_write q regs to linear dest (lane*16B) == DMA layout
#define QST(PAR) do {                                                         \
    *(int4*)&qbuf[w][PAR][0 * 256 + l * 4] = qr0;                             \
    *(int4*)&qbuf[w][PAR][1 * 256 + l * 4] = qr1;                             \
    *(int4*)&qbuf[w][PAR][2 * 256 + l * 4] = qr2;                             \
    *(int4*)&qbuf[w][PAR][3 * 256 + l * 4] = qr3;                             \
    } while (0)

#define STEP(PAR, S, XV) do {                                                 \
    const int4 q = *(const int4*)((const char*)qbuf[w][PAR] + r * 256         \
                                  + (((((S) << 2) + g) ^ r) << 4));           \
    uint4 ub = {                                                              \
        bf16pk((float)((q.x << 28) >> 28), (float)((q.x << 24) >> 28)),       \
        bf16pk((float)((q.y << 28) >> 28), (float)((q.y << 24) >> 28)),       \
        bf16pk((float)((q.z << 28) >> 28), (float)((q.z << 24) >> 28)),       \
        bf16pk((float)((q.w << 28) >> 28), (float)((q.w << 24) >> 28))        \
    };                                                                        \
    short8v bfrag = __builtin_bit_cast(short8v, ub);                          \
    short8v afrag = __builtin_bit_cast(short8v, XV);                          \
    acc = __builtin_amdgcn_mfma_f32_16x16x32_bf16(afrag, bfrag, acc, 0, 0, 0);\
    } while (0)

#define COMPUTE(PAR, B0, B1, B2, B3) do {                                     \
    STEP(PAR, 0, B0); STEP(PAR, 1, B1); STEP(PAR, 2, B2); STEP(PAR, 3, B3);   \
    } while (0)

    // BODY(c): literal PAR=c&1, NPAR=(c+1)&1, x buffers alternate A/B
    // entry: LDS[PAR]=q(c) written; x(c) resident in CURBUF; q(c+1),x(c+1)
    // in flight [8 outstanding]
#define BODY(PAR, NPAR, CB0, CB1, CB2, CB3, NB0, NB1, NB2, NB3, Cp2)          \
    do {                                                                      \
        WAITL(); SCHED0();                                                    \
        COMPUTE(PAR, CB0, CB1, CB2, CB3);                                     \
        SCHED0(); WAITV(4); SCHED0();      /* q(c+1) regs arrived */          \
        QST(NPAR);                                                            \
        QLD(Cp2); XLD(Cp2, CB0, CB1, CB2, CB3);  /* reuse consumed bufs */    \
        SCHED0(); WAITV(8); SCHED0();      /* x(c+1) resident */              \
    } while (0)

    // ---- prologue
    QLD(0); XLD(0, xa0, xa1, xa2, xa3);           // out: 8
    WAITV(4); SCHED0();                           // q(0) arrived
    QST(0);
    QLD(1); XLD(1, xb0, xb1, xb2r, xb3);          // out: x(0)4 + 8
    WAITV(8); SCHED0();                           // x(0) resident

    BODY(0, 1, xa0, xa1, xa2, xa3, xb0, xb1, xb2r, xb3, 2);
    BODY(1, 0, xb0, xb1, xb2r, xb3, xa0, xa1, xa2, xa3, 3);
    BODY(0, 1, xa0, xa1, xa2, xa3, xb0, xb1, xb2r, xb3, 4);
    BODY(1, 0, xb0, xb1, xb2r, xb3, xa0, xa1, xa2, xa3, 5);
    BODY(0, 1, xa0, xa1, xa2, xa3, xb0, xb1, xb2r, xb3, 6);
    BODY(1, 0, xb0, xb1, xb2r, xb3, xa0, xa1, xa2, xa3, 7);
    // c=6: no c+2 issue; retire q(7) then x(7)
    WAITL(); SCHED0();
    COMPUTE(0, xa0, xa1, xa2, xa3);
    SCHED0(); WAITV(4); SCHED0();                 // q(7) arrived
    QST(1);
    WAITV(0); SCHED0();                           // x(7) resident
    // c=7
    WAITL(); SCHED0();
    COMPUTE(1, xb0, xb1, xb2r, xb3);

#undef QLD
#undef XLD
#undef QST
#undef STEP
#undef COMPUTE
#undef BODY

    // ---- cross-wave K reduction; D map: col=lane&15 (out), row=(lane>>4)*4+j
    red[w][g * 4 + 0][r] = acc[0];
    red[w][g * 4 + 1][r] = acc[1];
    red[w][g * 4 + 2][r] = acc[2];
    red[w][g * 4 + 3][r] = acc[3];
    __syncthreads();

    if (t < 256) {
        const int b = t >> 4;
        const int o = t & 15;
        const int oc = obase + o;
        float v = 0.f;
        #pragma unroll
        for (int i = 0; i < 8; ++i) v += red[i][b][o];
        out[b * OUT_N + oc] = v * scale[oc >> 7] + bias[oc];
    }
}

extern "C" void kernel_launch(void* const* d_in, const int* in_sizes, int n_in,
                              void* d_out, int out_size, void* d_ws, size_t ws_size,
                              hipStream_t stream) {
    (void)in_sizes; (void)n_in; (void)ws_size; (void)out_size;
    const float* x     = (const float*)d_in[0];
    const int*   qp    = (const int*)d_in[1];
    const float* scale = (const float*)d_in[2];
    const float* bias  = (const float*)d_in[3];
    float*       out   = (float*)d_out;
    uint4*       xb2   = (uint4*)d_ws;     // 256 KB permuted bf16 x

    xconv_kernel<<<dim3(64), dim3(256), 0, stream>>>(x, xb2);
    qlin_mfma_kernel<<<dim3(OUT_N / 16), dim3(512), 0, stream>>>(qp, xb2, scale, bias, out);
}